// Round 1
// baseline (244.748 us; speedup 1.0000x reference)
//
#include <hip/hip_runtime.h>
#include <stdint.h>

#define B_ROWS 4096
#define NTOT   8192
#define D0     2048
#define D1     128
#define TAU    112.0f

// ---- workspace layout (bytes) ----
#define OFF_ACC   0        // double  signed sum of joint entries
#define OFF_S0    8        // double  sum of squared f0 entries
#define OFF_BW    16       // float   bandwidth0 (already /4)
#define OFF_CNT   20       // unsigned candidate count
#define OFF_M0    32       // float[2048] column sums of f0
#define OFF_SQ1   8320     // float[8192] row sq-norms of f1
#define OFF_T1    41216    // _Float16[8192*128] fp16 copy of f1
#define OFF_CAND  2138368  // uint2[] candidate pairs
#define ZERO_BYTES 8224

typedef _Float16 half8 __attribute__((ext_vector_type(8)));
typedef _Float16 half2v __attribute__((ext_vector_type(2)));
typedef float f32x4 __attribute__((ext_vector_type(4)));

#define LDSTRIDE 88   // fp16 elems per LDS row (64 data + 24 pad; 176B, 16B-aligned, 2-way banks)

// ---- Pass 0a: fp16 convert f1 + row squared norms -------------------------
__global__ void p0a(const float* __restrict__ src1, const float* __restrict__ tar1, char* __restrict__ ws) {
    int wave = threadIdx.x >> 6, lane = threadIdx.x & 63;
    int row = blockIdx.x * 4 + wave;
    const float2* rp = (const float2*)(row < B_ROWS ? src1 + (size_t)row * D1
                                                    : tar1 + (size_t)(row - B_ROWS) * D1);
    float2 v = rp[lane];
    float sq = v.x * v.x + v.y * v.y;
    #pragma unroll
    for (int off = 32; off; off >>= 1) sq += __shfl_down(sq, off);
    if (lane == 0) ((float*)(ws + OFF_SQ1))[row] = sq;
    half2v h; h[0] = (_Float16)v.x; h[1] = (_Float16)v.y;
    ((half2v*)(ws + OFF_T1))[(size_t)row * 64 + lane] = h;
}

// ---- Pass 0b: column sums + total sq of f0 (for closed-form sum(l2)) ------
__global__ void p0b(const float* __restrict__ src0, const float* __restrict__ tar0, char* __restrict__ ws) {
    int d = blockIdx.x * 256 + threadIdx.x;
    int rbase = blockIdx.y * 128;
    const float* base = rbase < B_ROWS ? src0 + (size_t)rbase * D0
                                       : tar0 + (size_t)(rbase - B_ROWS) * D0;
    float cs = 0.f, sq = 0.f;
    for (int r = 0; r < 128; r++) {
        float v = base[(size_t)r * D0 + d];
        cs += v; sq += v * v;
    }
    atomicAdd(&((float*)(ws + OFF_M0))[d], cs);
    #pragma unroll
    for (int off = 32; off; off >>= 1) sq += __shfl_down(sq, off);
    __shared__ float red[4];
    int lane = threadIdx.x & 63, wave = threadIdx.x >> 6;
    if (lane == 0) red[wave] = sq;
    __syncthreads();
    if (threadIdx.x == 0)
        atomicAdd((double*)(ws + OFF_S0), (double)(red[0] + red[1] + red[2] + red[3]));
}

// ---- Pass 0c: bandwidth0 = (2n*S0 - 2*||m||^2)/(n^2-n)/4 ------------------
__global__ void p0c(char* __restrict__ ws) {
    const float* m0 = (const float*)(ws + OFF_M0);
    float s = 0.f;
    for (int j = threadIdx.x; j < 2048; j += 256) { float v = m0[j]; s += v * v; }
    #pragma unroll
    for (int off = 32; off; off >>= 1) s += __shfl_down(s, off);
    __shared__ float red[4];
    int lane = threadIdx.x & 63, wave = threadIdx.x >> 6;
    if (lane == 0) red[wave] = s;
    __syncthreads();
    if (threadIdx.x == 0) {
        double m2 = (double)red[0] + red[1] + red[2] + red[3];
        double S0 = *(double*)(ws + OFF_S0);
        double lsum = 2.0 * (double)NTOT * S0 - 2.0 * m2;
        double bw = lsum / ((double)NTOT * NTOT - NTOT) / 4.0;  // /kernel_mul^(5//2)
        *(float*)(ws + OFF_BW) = (float)bw;
    }
}

// ---- Phase A: pairwise l2 on feature-1 via fp16 MFMA, emit candidates -----
__global__ __launch_bounds__(256) void phaseA(char* __restrict__ ws, unsigned cap) {
    int bi = blockIdx.y, bj = blockIdx.x;
    if (bj < bi) return;  // triangular: block-uniform branch
    __shared__ __align__(16) _Float16 At[128 * LDSTRIDE];
    __shared__ __align__(16) _Float16 Bt[128 * LDSTRIDE];
    const uint4* t1 = (const uint4*)(ws + OFF_T1);  // 16 uint4 per 128-elem row
    int t = threadIdx.x;
    int lane = t & 63, wave = t >> 6;
    int wm = wave & 1, wn = wave >> 1;
    int quad = lane >> 4;
    int Abase = bi * 128, Bbase = bj * 128;

    f32x4 acc[4][4];
    #pragma unroll
    for (int i = 0; i < 4; i++)
        #pragma unroll
        for (int j = 0; j < 4; j++) acc[i][j] = (f32x4){0.f, 0.f, 0.f, 0.f};

    #pragma unroll
    for (int s = 0; s < 2; s++) {       // two K-halves of 64
        __syncthreads();
        #pragma unroll
        for (int i = 0; i < 4; i++) {   // 1024 16B-chunks per tile, 4/thread
            int q = t + 256 * i;
            int r = q >> 3, c = q & 7;
            uint4 va = t1[(size_t)(Abase + r) * 16 + s * 8 + c];
            *(uint4*)((char*)At + r * (LDSTRIDE * 2) + c * 16) = va;
            uint4 vb = t1[(size_t)(Bbase + r) * 16 + s * 8 + c];
            *(uint4*)((char*)Bt + r * (LDSTRIDE * 2) + c * 16) = vb;
        }
        __syncthreads();
        #pragma unroll
        for (int kk = 0; kk < 2; kk++) {
            int koffB = kk * 64 + quad * 16;  // byte offset in LDS row
            half8 af[4], bf[4];
            #pragma unroll
            for (int mi = 0; mi < 4; mi++) {
                int row = wm * 64 + mi * 16 + (lane & 15);
                af[mi] = *(const half8*)((const char*)At + row * (LDSTRIDE * 2) + koffB);
            }
            #pragma unroll
            for (int nj = 0; nj < 4; nj++) {
                int row = wn * 64 + nj * 16 + (lane & 15);
                bf[nj] = *(const half8*)((const char*)Bt + row * (LDSTRIDE * 2) + koffB);
            }
            #pragma unroll
            for (int mi = 0; mi < 4; mi++)
                #pragma unroll
                for (int nj = 0; nj < 4; nj++)
                    acc[mi][nj] = __builtin_amdgcn_mfma_f32_16x16x32_f16(
                        af[mi], bf[nj], acc[mi][nj], 0, 0, 0);
        }
    }

    // epilogue: l2 = sq[a]+sq[b]-2*dot ; emit pairs below cutoff
    const float* sq1 = (const float*)(ws + OFF_SQ1);
    unsigned* cnt = (unsigned*)(ws + OFF_CNT);
    uint2* cand = (uint2*)(ws + OFF_CAND);
    f32x4 sqa[4];
    #pragma unroll
    for (int mi = 0; mi < 4; mi++)
        sqa[mi] = *(const f32x4*)&sq1[Abase + wm * 64 + mi * 16 + quad * 4];
    #pragma unroll
    for (int nj = 0; nj < 4; nj++) {
        int b = Bbase + wn * 64 + nj * 16 + (lane & 15);
        float sqb = sq1[b];
        #pragma unroll
        for (int mi = 0; mi < 4; mi++) {
            int abase = Abase + wm * 64 + mi * 16 + quad * 4;
            #pragma unroll
            for (int r = 0; r < 4; r++) {
                int a = abase + r;
                float l2 = sqa[mi][r] + sqb - 2.0f * acc[mi][nj][r];
                if (l2 < TAU && a <= b) {
                    unsigned idx = atomicAdd(cnt, 1u);
                    if (idx < cap) cand[idx] = make_uint2((unsigned)a, (unsigned)b);
                }
            }
        }
    }
}

// ---- Phase B: exact f32 evaluation of candidate pairs ---------------------
__global__ void phaseB(const float* __restrict__ src0, const float* __restrict__ src1,
                       const float* __restrict__ tar0, const float* __restrict__ tar1,
                       char* __restrict__ ws, unsigned cap) {
    unsigned cnt = *(const unsigned*)(ws + OFF_CNT);
    if (cnt > cap) cnt = cap;
    const uint2* cand = (const uint2*)(ws + OFF_CAND);
    double* acc = (double*)(ws + OFF_ACC);
    float bw = *(const float*)(ws + OFF_BW);
    int lane = threadIdx.x & 63;
    unsigned gw = blockIdx.x * (blockDim.x >> 6) + (threadIdx.x >> 6);
    unsigned nw = gridDim.x * (blockDim.x >> 6);
    for (unsigned i = gw; i < cnt; i += nw) {
        uint2 p = cand[i];
        unsigned a = p.x, b = p.y;
        if (a == b) {
            // l2_0 = l2_1 = 0 exactly -> k0 = 5, k1 = 1, s^2 = 1
            if (lane == 0) atomicAdd(acc, 5.0);
            continue;
        }
        const float* ra0 = a < B_ROWS ? src0 + (size_t)a * D0 : tar0 + (size_t)(a - B_ROWS) * D0;
        const float* rb0 = b < B_ROWS ? src0 + (size_t)b * D0 : tar0 + (size_t)(b - B_ROWS) * D0;
        const float* ra1 = a < B_ROWS ? src1 + (size_t)a * D1 : tar1 + (size_t)(a - B_ROWS) * D1;
        const float* rb1 = b < B_ROWS ? src1 + (size_t)b * D1 : tar1 + (size_t)(b - B_ROWS) * D1;
        float d1;
        {
            float2 x = ((const float2*)ra1)[lane];
            float2 y = ((const float2*)rb1)[lane];
            float dx = x.x - y.x, dy = x.y - y.y;
            d1 = dx * dx + dy * dy;
        }
        float d0 = 0.f;
        #pragma unroll
        for (int j = 0; j < 8; j++) {
            float4 x = ((const float4*)ra0)[lane + 64 * j];
            float4 y = ((const float4*)rb0)[lane + 64 * j];
            float dx = x.x - y.x, dy = x.y - y.y, dz = x.z - y.z, dw = x.w - y.w;
            d0 += dx * dx + dy * dy + dz * dz + dw * dw;
        }
        #pragma unroll
        for (int off = 32; off; off >>= 1) {
            d0 += __shfl_down(d0, off);
            d1 += __shfl_down(d1, off);
        }
        if (lane == 0) {
            float k1 = expf(-d1 / 1.68f);
            float k0 = 0.f, bwj = bw;
            #pragma unroll
            for (int j = 0; j < 5; j++) { k0 += expf(-d0 / bwj); bwj *= 2.0f; }
            float sgn = ((a < B_ROWS) == (b < B_ROWS)) ? 1.0f : -1.0f;
            atomicAdd(acc, (double)(2.0f * sgn * k0 * k1));  // x2: (a,b) and (b,a)
        }
    }
}

// ---- Final: mean ----------------------------------------------------------
__global__ void finalk(const char* __restrict__ ws, float* __restrict__ out) {
    if (threadIdx.x == 0 && blockIdx.x == 0) {
        double acc = *(const double*)(ws + OFF_ACC);
        out[0] = (float)(acc / ((double)B_ROWS * (double)B_ROWS));
    }
}

extern "C" void kernel_launch(void* const* d_in, const int* in_sizes, int n_in,
                              void* d_out, int out_size, void* d_ws, size_t ws_size,
                              hipStream_t stream) {
    const float* src0 = (const float*)d_in[0];
    const float* src1 = (const float*)d_in[1];
    const float* tar0 = (const float*)d_in[2];
    const float* tar1 = (const float*)d_in[3];
    char* ws = (char*)d_ws;
    unsigned cap = 0;
    if (ws_size > (size_t)OFF_CAND + 8) {
        size_t c = (ws_size - OFF_CAND) / 8;
        if (c > (size_t)4 * 1024 * 1024) c = (size_t)4 * 1024 * 1024;
        cap = (unsigned)c;
    }
    hipMemsetAsync(d_ws, 0, ZERO_BYTES, stream);
    p0a<<<2048, 256, 0, stream>>>(src1, tar1, ws);
    p0b<<<dim3(8, 64), 256, 0, stream>>>(src0, tar0, ws);
    p0c<<<1, 256, 0, stream>>>(ws);
    phaseA<<<dim3(64, 64), 256, 0, stream>>>(ws, cap);
    phaseB<<<128, 256, 0, stream>>>(src0, src1, tar0, tar1, ws, cap);
    finalk<<<1, 64, 0, stream>>>(ws, (float*)d_out);
}

// Round 2
// 151.192 us; speedup vs baseline: 1.6188x; 1.6188x over previous
//
#include <hip/hip_runtime.h>
#include <stdint.h>

#define B_ROWS 4096
#define NTOT   8192
#define D0     2048
#define D1     128
#define TAU    112.0f

// ---- workspace layout (bytes) ----
#define OFF_ACC   0        // double  signed sum of OFF-DIAGONAL joint entries
#define OFF_S0    8        // double  sum of squared f0 entries
#define OFF_BW    16       // float   bandwidth0 (already /4)
#define OFF_CNT   20       // unsigned candidate count
#define OFF_M0    32       // float[2048] column sums of f0
#define OFF_SQ1   8320     // float[8192] row sq-norms of f1
#define OFF_T1    41216    // _Float16[8192*128] fp16 copy of f1
#define OFF_CAND  2138368  // uint2[] candidate pairs
#define ZERO_BYTES 8224

typedef _Float16 half8 __attribute__((ext_vector_type(8)));
typedef _Float16 half2v __attribute__((ext_vector_type(2)));
typedef float f32x4 __attribute__((ext_vector_type(4)));

#define LDSTRIDE 88   // fp16 elems per LDS row (64 data + 24 pad; 176B, 16B-aligned, 2-way banks)

// ---- Pass 0a: fp16 convert f1 + row squared norms -------------------------
__global__ void p0a(const float* __restrict__ src1, const float* __restrict__ tar1, char* __restrict__ ws) {
    int wave = threadIdx.x >> 6, lane = threadIdx.x & 63;
    int row = blockIdx.x * 4 + wave;
    const float2* rp = (const float2*)(row < B_ROWS ? src1 + (size_t)row * D1
                                                    : tar1 + (size_t)(row - B_ROWS) * D1);
    float2 v = rp[lane];
    float sq = v.x * v.x + v.y * v.y;
    #pragma unroll
    for (int off = 32; off; off >>= 1) sq += __shfl_down(sq, off);
    if (lane == 0) ((float*)(ws + OFF_SQ1))[row] = sq;
    half2v h; h[0] = (_Float16)v.x; h[1] = (_Float16)v.y;
    ((half2v*)(ws + OFF_T1))[(size_t)row * 64 + lane] = h;
}

// ---- Pass 0b: column sums + total sq of f0 (for closed-form sum(l2)) ------
// float4 loads; grid (2,128): 256 blocks x 256 thr, 64 rows per y-block.
__global__ void p0b(const float* __restrict__ src0, const float* __restrict__ tar0, char* __restrict__ ws) {
    int d4 = blockIdx.x * 256 + threadIdx.x;   // float4-column, 0..511
    int rbase = blockIdx.y * 64;
    const float4* base = (const float4*)(rbase < B_ROWS ? src0 + (size_t)rbase * D0
                                                        : tar0 + (size_t)(rbase - B_ROWS) * D0);
    float4 cs = {0.f, 0.f, 0.f, 0.f};
    float sq = 0.f;
    for (int r = 0; r < 64; r++) {
        float4 v = base[(size_t)r * 512 + d4];
        cs.x += v.x; cs.y += v.y; cs.z += v.z; cs.w += v.w;
        sq += v.x * v.x + v.y * v.y + v.z * v.z + v.w * v.w;
    }
    float* m0 = (float*)(ws + OFF_M0);
    atomicAdd(&m0[d4 * 4 + 0], cs.x);
    atomicAdd(&m0[d4 * 4 + 1], cs.y);
    atomicAdd(&m0[d4 * 4 + 2], cs.z);
    atomicAdd(&m0[d4 * 4 + 3], cs.w);
    #pragma unroll
    for (int off = 32; off; off >>= 1) sq += __shfl_down(sq, off);
    __shared__ float red[4];
    int lane = threadIdx.x & 63, wave = threadIdx.x >> 6;
    if (lane == 0) red[wave] = sq;
    __syncthreads();
    if (threadIdx.x == 0)
        atomicAdd((double*)(ws + OFF_S0), (double)(red[0] + red[1] + red[2] + red[3]));
}

// ---- Pass 0c: bandwidth0 = (2n*S0 - 2*||m||^2)/(n^2-n)/4 ------------------
__global__ void p0c(char* __restrict__ ws) {
    const float* m0 = (const float*)(ws + OFF_M0);
    float s = 0.f;
    for (int j = threadIdx.x; j < 2048; j += 256) { float v = m0[j]; s += v * v; }
    #pragma unroll
    for (int off = 32; off; off >>= 1) s += __shfl_down(s, off);
    __shared__ float red[4];
    int lane = threadIdx.x & 63, wave = threadIdx.x >> 6;
    if (lane == 0) red[wave] = s;
    __syncthreads();
    if (threadIdx.x == 0) {
        double m2 = (double)red[0] + red[1] + red[2] + red[3];
        double S0 = *(double*)(ws + OFF_S0);
        double lsum = 2.0 * (double)NTOT * S0 - 2.0 * m2;
        double bw = lsum / ((double)NTOT * NTOT - NTOT) / 4.0;  // /kernel_mul^(5//2)
        *(float*)(ws + OFF_BW) = (float)bw;
    }
}

// ---- Phase A: pairwise l2 on feature-1 via fp16 MFMA, emit candidates -----
// Emits STRICT a<b pairs only; the 8192 diagonal entries contribute the
// data-independent constant 8192*5 added in finalk (l2=0 exactly on diag).
__global__ __launch_bounds__(256) void phaseA(char* __restrict__ ws, unsigned cap) {
    int bi = blockIdx.y, bj = blockIdx.x;
    if (bj < bi) return;  // triangular: block-uniform branch
    __shared__ __align__(16) _Float16 At[128 * LDSTRIDE];
    __shared__ __align__(16) _Float16 Bt[128 * LDSTRIDE];
    const uint4* t1 = (const uint4*)(ws + OFF_T1);  // 16 uint4 per 128-elem row
    int t = threadIdx.x;
    int lane = t & 63, wave = t >> 6;
    int wm = wave & 1, wn = wave >> 1;
    int quad = lane >> 4;
    int Abase = bi * 128, Bbase = bj * 128;

    f32x4 acc[4][4];
    #pragma unroll
    for (int i = 0; i < 4; i++)
        #pragma unroll
        for (int j = 0; j < 4; j++) acc[i][j] = (f32x4){0.f, 0.f, 0.f, 0.f};

    #pragma unroll
    for (int s = 0; s < 2; s++) {       // two K-halves of 64
        __syncthreads();
        #pragma unroll
        for (int i = 0; i < 4; i++) {   // 1024 16B-chunks per tile, 4/thread
            int q = t + 256 * i;
            int r = q >> 3, c = q & 7;
            uint4 va = t1[(size_t)(Abase + r) * 16 + s * 8 + c];
            *(uint4*)((char*)At + r * (LDSTRIDE * 2) + c * 16) = va;
            uint4 vb = t1[(size_t)(Bbase + r) * 16 + s * 8 + c];
            *(uint4*)((char*)Bt + r * (LDSTRIDE * 2) + c * 16) = vb;
        }
        __syncthreads();
        #pragma unroll
        for (int kk = 0; kk < 2; kk++) {
            int koffB = kk * 64 + quad * 16;  // byte offset in LDS row
            half8 af[4], bf[4];
            #pragma unroll
            for (int mi = 0; mi < 4; mi++) {
                int row = wm * 64 + mi * 16 + (lane & 15);
                af[mi] = *(const half8*)((const char*)At + row * (LDSTRIDE * 2) + koffB);
            }
            #pragma unroll
            for (int nj = 0; nj < 4; nj++) {
                int row = wn * 64 + nj * 16 + (lane & 15);
                bf[nj] = *(const half8*)((const char*)Bt + row * (LDSTRIDE * 2) + koffB);
            }
            #pragma unroll
            for (int mi = 0; mi < 4; mi++)
                #pragma unroll
                for (int nj = 0; nj < 4; nj++)
                    acc[mi][nj] = __builtin_amdgcn_mfma_f32_16x16x32_f16(
                        af[mi], bf[nj], acc[mi][nj], 0, 0, 0);
        }
    }

    // epilogue: l2 = sq[a]+sq[b]-2*dot ; emit strict a<b pairs below cutoff
    const float* sq1 = (const float*)(ws + OFF_SQ1);
    unsigned* cnt = (unsigned*)(ws + OFF_CNT);
    uint2* cand = (uint2*)(ws + OFF_CAND);
    f32x4 sqa[4];
    #pragma unroll
    for (int mi = 0; mi < 4; mi++)
        sqa[mi] = *(const f32x4*)&sq1[Abase + wm * 64 + mi * 16 + quad * 4];
    #pragma unroll
    for (int nj = 0; nj < 4; nj++) {
        int b = Bbase + wn * 64 + nj * 16 + (lane & 15);
        float sqb = sq1[b];
        #pragma unroll
        for (int mi = 0; mi < 4; mi++) {
            int abase = Abase + wm * 64 + mi * 16 + quad * 4;
            #pragma unroll
            for (int r = 0; r < 4; r++) {
                int a = abase + r;
                float l2 = sqa[mi][r] + sqb - 2.0f * acc[mi][nj][r];
                if (l2 < TAU && a < b) {
                    unsigned idx = atomicAdd(cnt, 1u);
                    if (idx < cap) cand[idx] = make_uint2((unsigned)a, (unsigned)b);
                }
            }
        }
    }
}

// ---- Phase B: exact f32 evaluation of candidate pairs ---------------------
// Per-wave register accumulation -> per-block LDS reduce -> ONE atomic/block
// (R1 post-mortem: 8192 same-address f64 atomics serialized at ~12ns each
//  = 101us with all pipes idle).
__global__ void phaseB(const float* __restrict__ src0, const float* __restrict__ src1,
                       const float* __restrict__ tar0, const float* __restrict__ tar1,
                       char* __restrict__ ws, unsigned cap) {
    unsigned cnt = *(const unsigned*)(ws + OFF_CNT);
    if (cnt > cap) cnt = cap;
    const uint2* cand = (const uint2*)(ws + OFF_CAND);
    float bw = *(const float*)(ws + OFF_BW);
    int lane = threadIdx.x & 63, wave = threadIdx.x >> 6;
    unsigned gw = blockIdx.x * 4 + wave;
    unsigned nw = gridDim.x * 4;
    double lsum = 0.0;
    for (unsigned i = gw; i < cnt; i += nw) {
        uint2 p = cand[i];
        unsigned a = p.x, b = p.y;   // strict a<b by construction
        const float* ra0 = a < B_ROWS ? src0 + (size_t)a * D0 : tar0 + (size_t)(a - B_ROWS) * D0;
        const float* rb0 = b < B_ROWS ? src0 + (size_t)b * D0 : tar0 + (size_t)(b - B_ROWS) * D0;
        const float* ra1 = a < B_ROWS ? src1 + (size_t)a * D1 : tar1 + (size_t)(a - B_ROWS) * D1;
        const float* rb1 = b < B_ROWS ? src1 + (size_t)b * D1 : tar1 + (size_t)(b - B_ROWS) * D1;
        float d1;
        {
            float2 x = ((const float2*)ra1)[lane];
            float2 y = ((const float2*)rb1)[lane];
            float dx = x.x - y.x, dy = x.y - y.y;
            d1 = dx * dx + dy * dy;
        }
        float d0 = 0.f;
        #pragma unroll
        for (int j = 0; j < 8; j++) {
            float4 x = ((const float4*)ra0)[lane + 64 * j];
            float4 y = ((const float4*)rb0)[lane + 64 * j];
            float dx = x.x - y.x, dy = x.y - y.y, dz = x.z - y.z, dw = x.w - y.w;
            d0 += dx * dx + dy * dy + dz * dz + dw * dw;
        }
        #pragma unroll
        for (int off = 32; off; off >>= 1) {
            d0 += __shfl_down(d0, off);
            d1 += __shfl_down(d1, off);
        }
        if (lane == 0) {
            float k1 = expf(-d1 / 1.68f);
            float k0 = 0.f, bwj = bw;
            #pragma unroll
            for (int j = 0; j < 5; j++) { k0 += expf(-d0 / bwj); bwj *= 2.0f; }
            float sgn = ((a < B_ROWS) == (b < B_ROWS)) ? 1.0f : -1.0f;
            lsum += (double)(2.0f * sgn * k0 * k1);  // x2: (a,b) and (b,a)
        }
    }
    __shared__ double red[4];
    if (lane == 0) red[wave] = lsum;
    __syncthreads();
    if (threadIdx.x == 0)
        atomicAdd((double*)(ws + OFF_ACC), red[0] + red[1] + red[2] + red[3]);
}

// ---- Final: mean (diagonal contributes exactly 8192 * 5) ------------------
__global__ void finalk(const char* __restrict__ ws, float* __restrict__ out) {
    if (threadIdx.x == 0 && blockIdx.x == 0) {
        double acc = *(const double*)(ws + OFF_ACC);
        out[0] = (float)((acc + (double)NTOT * 5.0) / ((double)B_ROWS * (double)B_ROWS));
    }
}

extern "C" void kernel_launch(void* const* d_in, const int* in_sizes, int n_in,
                              void* d_out, int out_size, void* d_ws, size_t ws_size,
                              hipStream_t stream) {
    const float* src0 = (const float*)d_in[0];
    const float* src1 = (const float*)d_in[1];
    const float* tar0 = (const float*)d_in[2];
    const float* tar1 = (const float*)d_in[3];
    char* ws = (char*)d_ws;
    unsigned cap = 0;
    if (ws_size > (size_t)OFF_CAND + 8) {
        size_t c = (ws_size - OFF_CAND) / 8;
        if (c > (size_t)4 * 1024 * 1024) c = (size_t)4 * 1024 * 1024;
        cap = (unsigned)c;
    }
    hipMemsetAsync(d_ws, 0, ZERO_BYTES, stream);
    p0a<<<2048, 256, 0, stream>>>(src1, tar1, ws);
    p0b<<<dim3(2, 128), 256, 0, stream>>>(src0, tar0, ws);
    p0c<<<1, 256, 0, stream>>>(ws);
    phaseA<<<dim3(64, 64), 256, 0, stream>>>(ws, cap);
    phaseB<<<64, 256, 0, stream>>>(src0, src1, tar0, tar1, ws, cap);
    finalk<<<1, 64, 0, stream>>>(ws, (float*)d_out);
}

// Round 3
// 119.888 us; speedup vs baseline: 2.0415x; 1.2611x over previous
//
#include <hip/hip_runtime.h>
#include <stdint.h>

#define B_ROWS 4096
#define NTOT   8192
#define D0     2048
#define D1     128
#define TAU    112.0f

// ---- workspace layout (bytes) ----
#define OFF_ACC   0        // double  signed sum of OFF-DIAGONAL joint entries
#define OFF_S0    8        // double  sum of squared f0 entries
#define OFF_BW    16       // float   bandwidth0 (already /4)
#define OFF_CNT   20       // unsigned candidate count
#define OFF_M0    32       // float[2048] column sums of f0
#define OFF_SQ1   8320     // float[8192] row sq-norms of f1
#define OFF_T1    41216    // _Float16[8192*128] fp16 copy of f1
#define OFF_CAND  2138368  // uint2[] candidate pairs
#define ZERO_BYTES 8224

typedef _Float16 half8 __attribute__((ext_vector_type(8)));
typedef _Float16 half2v __attribute__((ext_vector_type(2)));
typedef float f32x4 __attribute__((ext_vector_type(4)));

#define LDSTRIDE 88   // fp16 elems per LDS row (64 data + 24 pad; 176B, 16B-aligned, 2-way banks)

// ---- Pass 0a: fp16 convert f1 + row squared norms -------------------------
__global__ void p0a(const float* __restrict__ src1, const float* __restrict__ tar1, char* __restrict__ ws) {
    int wave = threadIdx.x >> 6, lane = threadIdx.x & 63;
    int row = blockIdx.x * 4 + wave;
    const float2* rp = (const float2*)(row < B_ROWS ? src1 + (size_t)row * D1
                                                    : tar1 + (size_t)(row - B_ROWS) * D1);
    float2 v = rp[lane];
    float sq = v.x * v.x + v.y * v.y;
    #pragma unroll
    for (int off = 32; off; off >>= 1) sq += __shfl_down(sq, off);
    if (lane == 0) ((float*)(ws + OFF_SQ1))[row] = sq;
    half2v h; h[0] = (_Float16)v.x; h[1] = (_Float16)v.y;
    ((half2v*)(ws + OFF_T1))[(size_t)row * 64 + lane] = h;
}

// ---- Phase A: pairwise l2 on feature-1 via fp16 MFMA, emit candidates -----
// 1D grid of exactly 2080 upper-triangle 128x128 tiles (bj >= bi).
// Emits STRICT a<b pairs only; the 8192 diagonal entries contribute the
// data-independent constant 8192*5 added in finalk (l2=0 exactly on diag).
__global__ __launch_bounds__(256) void phaseA(char* __restrict__ ws, unsigned cap) {
    // unmap linear tile id -> (bi, bj), bj >= bi, 64x64 tile grid
    int tid = blockIdx.x;
    int bi = (int)((129.0 - sqrt(129.0 * 129.0 - 8.0 * (double)tid)) * 0.5);
    // S(bi) = bi*(129-bi)/2 ; fix rounding
    while (((bi + 1) * (129 - (bi + 1))) / 2 <= tid) bi++;
    while ((bi * (129 - bi)) / 2 > tid) bi--;
    int bj = bi + (tid - (bi * (129 - bi)) / 2);

    __shared__ __align__(16) _Float16 At[128 * LDSTRIDE];
    __shared__ __align__(16) _Float16 Bt[128 * LDSTRIDE];
    const uint4* t1 = (const uint4*)(ws + OFF_T1);  // 16 uint4 per 128-elem row
    int t = threadIdx.x;
    int lane = t & 63, wave = t >> 6;
    int wm = wave & 1, wn = wave >> 1;
    int quad = lane >> 4;
    int Abase = bi * 128, Bbase = bj * 128;

    f32x4 acc[4][4];
    #pragma unroll
    for (int i = 0; i < 4; i++)
        #pragma unroll
        for (int j = 0; j < 4; j++) acc[i][j] = (f32x4){0.f, 0.f, 0.f, 0.f};

    #pragma unroll
    for (int s = 0; s < 2; s++) {       // two K-halves of 64
        __syncthreads();
        #pragma unroll
        for (int i = 0; i < 4; i++) {   // 1024 16B-chunks per tile, 4/thread
            int q = t + 256 * i;
            int r = q >> 3, c = q & 7;
            uint4 va = t1[(size_t)(Abase + r) * 16 + s * 8 + c];
            *(uint4*)((char*)At + r * (LDSTRIDE * 2) + c * 16) = va;
            uint4 vb = t1[(size_t)(Bbase + r) * 16 + s * 8 + c];
            *(uint4*)((char*)Bt + r * (LDSTRIDE * 2) + c * 16) = vb;
        }
        __syncthreads();
        #pragma unroll
        for (int kk = 0; kk < 2; kk++) {
            int koffB = kk * 64 + quad * 16;  // byte offset in LDS row
            half8 af[4], bf[4];
            #pragma unroll
            for (int mi = 0; mi < 4; mi++) {
                int row = wm * 64 + mi * 16 + (lane & 15);
                af[mi] = *(const half8*)((const char*)At + row * (LDSTRIDE * 2) + koffB);
            }
            #pragma unroll
            for (int nj = 0; nj < 4; nj++) {
                int row = wn * 64 + nj * 16 + (lane & 15);
                bf[nj] = *(const half8*)((const char*)Bt + row * (LDSTRIDE * 2) + koffB);
            }
            #pragma unroll
            for (int mi = 0; mi < 4; mi++)
                #pragma unroll
                for (int nj = 0; nj < 4; nj++)
                    acc[mi][nj] = __builtin_amdgcn_mfma_f32_16x16x32_f16(
                        af[mi], bf[nj], acc[mi][nj], 0, 0, 0);
        }
    }

    // epilogue: l2 = sq[a]+sq[b]-2*dot ; emit strict a<b pairs below cutoff
    const float* sq1 = (const float*)(ws + OFF_SQ1);
    unsigned* cnt = (unsigned*)(ws + OFF_CNT);
    uint2* cand = (uint2*)(ws + OFF_CAND);
    f32x4 sqa[4];
    #pragma unroll
    for (int mi = 0; mi < 4; mi++)
        sqa[mi] = *(const f32x4*)&sq1[Abase + wm * 64 + mi * 16 + quad * 4];
    #pragma unroll
    for (int nj = 0; nj < 4; nj++) {
        int b = Bbase + wn * 64 + nj * 16 + (lane & 15);
        float sqb = sq1[b];
        #pragma unroll
        for (int mi = 0; mi < 4; mi++) {
            int abase = Abase + wm * 64 + mi * 16 + quad * 4;
            #pragma unroll
            for (int r = 0; r < 4; r++) {
                int a = abase + r;
                float l2 = sqa[mi][r] + sqb - 2.0f * acc[mi][nj][r];
                if (l2 < TAU && a < b) {
                    unsigned idx = atomicAdd(cnt, 1u);
                    if (idx < cap) cand[idx] = make_uint2((unsigned)a, (unsigned)b);
                }
            }
        }
    }
}

// ---- bwk1: column sums + total sq of f0 — ONLY if candidates exist --------
// (R2 post-mortem: this 64 MB pass fed bandwidth0, which is consumed only by
//  off-diagonal candidates; gate it on cnt>0 so the common case skips HBM.)
__global__ void bwk1(const float* __restrict__ src0, const float* __restrict__ tar0, char* __restrict__ ws) {
    if (*(volatile unsigned*)(ws + OFF_CNT) == 0) return;
    int d4 = blockIdx.x * 256 + threadIdx.x;   // float4-column, 0..511
    int rbase = blockIdx.y * 64;
    const float4* base = (const float4*)(rbase < B_ROWS ? src0 + (size_t)rbase * D0
                                                        : tar0 + (size_t)(rbase - B_ROWS) * D0);
    float4 cs = {0.f, 0.f, 0.f, 0.f};
    float sq = 0.f;
    for (int r = 0; r < 64; r++) {
        float4 v = base[(size_t)r * 512 + d4];
        cs.x += v.x; cs.y += v.y; cs.z += v.z; cs.w += v.w;
        sq += v.x * v.x + v.y * v.y + v.z * v.z + v.w * v.w;
    }
    float* m0 = (float*)(ws + OFF_M0);
    atomicAdd(&m0[d4 * 4 + 0], cs.x);
    atomicAdd(&m0[d4 * 4 + 1], cs.y);
    atomicAdd(&m0[d4 * 4 + 2], cs.z);
    atomicAdd(&m0[d4 * 4 + 3], cs.w);
    #pragma unroll
    for (int off = 32; off; off >>= 1) sq += __shfl_down(sq, off);
    __shared__ float red[4];
    int lane = threadIdx.x & 63, wave = threadIdx.x >> 6;
    if (lane == 0) red[wave] = sq;
    __syncthreads();
    if (threadIdx.x == 0)
        atomicAdd((double*)(ws + OFF_S0), (double)(red[0] + red[1] + red[2] + red[3]));
}

// ---- bwk2: bandwidth0 = (2n*S0 - 2*||m||^2)/(n^2-n)/4 — only if cnt>0 ----
__global__ void bwk2(char* __restrict__ ws) {
    if (*(volatile unsigned*)(ws + OFF_CNT) == 0) return;
    const float* m0 = (const float*)(ws + OFF_M0);
    float s = 0.f;
    for (int j = threadIdx.x; j < 2048; j += 256) { float v = m0[j]; s += v * v; }
    #pragma unroll
    for (int off = 32; off; off >>= 1) s += __shfl_down(s, off);
    __shared__ float red[4];
    int lane = threadIdx.x & 63, wave = threadIdx.x >> 6;
    if (lane == 0) red[wave] = s;
    __syncthreads();
    if (threadIdx.x == 0) {
        double m2 = (double)red[0] + red[1] + red[2] + red[3];
        double S0 = *(double*)(ws + OFF_S0);
        double lsum = 2.0 * (double)NTOT * S0 - 2.0 * m2;
        double bw = lsum / ((double)NTOT * NTOT - NTOT) / 4.0;  // /kernel_mul^(5//2)
        *(float*)(ws + OFF_BW) = (float)bw;
    }
}

// ---- Phase B: exact f32 evaluation of candidate pairs ---------------------
// Per-wave register accumulation -> per-block LDS reduce -> ONE atomic/block.
__global__ void phaseB(const float* __restrict__ src0, const float* __restrict__ src1,
                       const float* __restrict__ tar0, const float* __restrict__ tar1,
                       char* __restrict__ ws, unsigned cap) {
    unsigned cnt = *(const unsigned*)(ws + OFF_CNT);
    if (cnt == 0) return;
    if (cnt > cap) cnt = cap;
    const uint2* cand = (const uint2*)(ws + OFF_CAND);
    float bw = *(const float*)(ws + OFF_BW);
    int lane = threadIdx.x & 63, wave = threadIdx.x >> 6;
    unsigned gw = blockIdx.x * 4 + wave;
    unsigned nw = gridDim.x * 4;
    double lsum = 0.0;
    for (unsigned i = gw; i < cnt; i += nw) {
        uint2 p = cand[i];
        unsigned a = p.x, b = p.y;   // strict a<b by construction
        const float* ra0 = a < B_ROWS ? src0 + (size_t)a * D0 : tar0 + (size_t)(a - B_ROWS) * D0;
        const float* rb0 = b < B_ROWS ? src0 + (size_t)b * D0 : tar0 + (size_t)(b - B_ROWS) * D0;
        const float* ra1 = a < B_ROWS ? src1 + (size_t)a * D1 : tar1 + (size_t)(a - B_ROWS) * D1;
        const float* rb1 = b < B_ROWS ? src1 + (size_t)b * D1 : tar1 + (size_t)(b - B_ROWS) * D1;
        float d1;
        {
            float2 x = ((const float2*)ra1)[lane];
            float2 y = ((const float2*)rb1)[lane];
            float dx = x.x - y.x, dy = x.y - y.y;
            d1 = dx * dx + dy * dy;
        }
        float d0 = 0.f;
        #pragma unroll
        for (int j = 0; j < 8; j++) {
            float4 x = ((const float4*)ra0)[lane + 64 * j];
            float4 y = ((const float4*)rb0)[lane + 64 * j];
            float dx = x.x - y.x, dy = x.y - y.y, dz = x.z - y.z, dw = x.w - y.w;
            d0 += dx * dx + dy * dy + dz * dz + dw * dw;
        }
        #pragma unroll
        for (int off = 32; off; off >>= 1) {
            d0 += __shfl_down(d0, off);
            d1 += __shfl_down(d1, off);
        }
        if (lane == 0) {
            float k1 = expf(-d1 / 1.68f);
            float k0 = 0.f, bwj = bw;
            #pragma unroll
            for (int j = 0; j < 5; j++) { k0 += expf(-d0 / bwj); bwj *= 2.0f; }
            float sgn = ((a < B_ROWS) == (b < B_ROWS)) ? 1.0f : -1.0f;
            lsum += (double)(2.0f * sgn * k0 * k1);  // x2: (a,b) and (b,a)
        }
    }
    __shared__ double red[4];
    if (lane == 0) red[wave] = lsum;
    __syncthreads();
    if (threadIdx.x == 0)
        atomicAdd((double*)(ws + OFF_ACC), red[0] + red[1] + red[2] + red[3]);
}

// ---- Final: mean (diagonal contributes exactly 8192 * 5) ------------------
__global__ void finalk(const char* __restrict__ ws, float* __restrict__ out) {
    if (threadIdx.x == 0 && blockIdx.x == 0) {
        double acc = *(const double*)(ws + OFF_ACC);
        out[0] = (float)((acc + (double)NTOT * 5.0) / ((double)B_ROWS * (double)B_ROWS));
    }
}

extern "C" void kernel_launch(void* const* d_in, const int* in_sizes, int n_in,
                              void* d_out, int out_size, void* d_ws, size_t ws_size,
                              hipStream_t stream) {
    const float* src0 = (const float*)d_in[0];
    const float* src1 = (const float*)d_in[1];
    const float* tar0 = (const float*)d_in[2];
    const float* tar1 = (const float*)d_in[3];
    char* ws = (char*)d_ws;
    unsigned cap = 0;
    if (ws_size > (size_t)OFF_CAND + 8) {
        size_t c = (ws_size - OFF_CAND) / 8;
        if (c > (size_t)4 * 1024 * 1024) c = (size_t)4 * 1024 * 1024;
        cap = (unsigned)c;
    }
    hipMemsetAsync(d_ws, 0, ZERO_BYTES, stream);
    p0a<<<2048, 256, 0, stream>>>(src1, tar1, ws);
    phaseA<<<2080, 256, 0, stream>>>(ws, cap);
    bwk1<<<dim3(2, 128), 256, 0, stream>>>(src0, tar0, ws);
    bwk2<<<1, 256, 0, stream>>>(ws);
    phaseB<<<64, 256, 0, stream>>>(src0, src1, tar0, tar1, ws, cap);
    finalk<<<1, 64, 0, stream>>>(ws, (float*)d_out);
}

// Round 4
// 117.587 us; speedup vs baseline: 2.0814x; 1.0196x over previous
//
#include <hip/hip_runtime.h>
#include <stdint.h>

#define B_ROWS 4096
#define NTOT   8192
#define D0     2048
#define D1     128
#define TAU    112.0f

// ---- workspace layout (bytes) ----
#define OFF_ACC   0        // double  signed sum of OFF-DIAGONAL joint entries
#define OFF_S0    8        // double  sum of squared f0 entries
#define OFF_BW    16       // float   (unused scratch)
#define OFF_CNT   20       // unsigned candidate count
#define OFF_DONE  24       // unsigned phaseB completion counter
#define OFF_M0    32       // float[2048] column sums of f0
#define OFF_SQ1   8320     // float[8192] row sq-norms of f1
#define OFF_T1    41216    // _Float16[8192*128] fp16 copy of f1
#define OFF_CAND  2138368  // uint2[] candidate pairs
#define ZERO_WORDS 2056    // bytes 0..8223: header + M0

typedef _Float16 half8 __attribute__((ext_vector_type(8)));
typedef _Float16 half2v __attribute__((ext_vector_type(2)));
typedef float f32x4 __attribute__((ext_vector_type(4)));

#define LDSTRIDE 88   // fp16 elems per LDS row (64 data + 24 pad; 176B, 16B-aligned, 2-way banks)

// ---- Pass 0a: fp16 convert f1 + row squared norms + ws header zeroing -----
__global__ void p0a(const float* __restrict__ src1, const float* __restrict__ tar1, char* __restrict__ ws) {
    // block 0 zeroes the accumulator/counter/M0 region (replaces memset node;
    // disjoint from all p0a writes, precedes all consumers in stream order)
    if (blockIdx.x == 0) {
        unsigned* w = (unsigned*)ws;
        for (int i = threadIdx.x; i < ZERO_WORDS; i += 256) w[i] = 0;
    }
    int wave = threadIdx.x >> 6, lane = threadIdx.x & 63;
    int row = blockIdx.x * 4 + wave;
    const float2* rp = (const float2*)(row < B_ROWS ? src1 + (size_t)row * D1
                                                    : tar1 + (size_t)(row - B_ROWS) * D1);
    float2 v = rp[lane];
    float sq = v.x * v.x + v.y * v.y;
    #pragma unroll
    for (int off = 32; off; off >>= 1) sq += __shfl_down(sq, off);
    if (lane == 0) ((float*)(ws + OFF_SQ1))[row] = sq;
    half2v h; h[0] = (_Float16)v.x; h[1] = (_Float16)v.y;
    ((half2v*)(ws + OFF_T1))[(size_t)row * 64 + lane] = h;
}

// ---- Phase A: pairwise l2 on feature-1 via fp16 MFMA, emit candidates -----
// 1D grid of exactly 2080 upper-triangle 128x128 tiles (bj >= bi).
// Emits STRICT a<b pairs only; the 8192 diagonal entries contribute the
// data-independent constant 8192*5 added at the end (l2=0 exactly on diag).
__global__ __launch_bounds__(256) void phaseA(char* __restrict__ ws, unsigned cap) {
    // unmap linear tile id -> (bi, bj), bj >= bi, 64x64 tile grid
    int tid = blockIdx.x;
    int bi = (int)((129.0 - sqrt(129.0 * 129.0 - 8.0 * (double)tid)) * 0.5);
    while (((bi + 1) * (129 - (bi + 1))) / 2 <= tid) bi++;
    while ((bi * (129 - bi)) / 2 > tid) bi--;
    int bj = bi + (tid - (bi * (129 - bi)) / 2);

    __shared__ __align__(16) _Float16 At[128 * LDSTRIDE];
    __shared__ __align__(16) _Float16 Bt[128 * LDSTRIDE];
    const uint4* t1 = (const uint4*)(ws + OFF_T1);  // 16 uint4 per 128-elem row
    int t = threadIdx.x;
    int lane = t & 63, wave = t >> 6;
    int wm = wave & 1, wn = wave >> 1;
    int quad = lane >> 4;
    int Abase = bi * 128, Bbase = bj * 128;

    f32x4 acc[4][4];
    #pragma unroll
    for (int i = 0; i < 4; i++)
        #pragma unroll
        for (int j = 0; j < 4; j++) acc[i][j] = (f32x4){0.f, 0.f, 0.f, 0.f};

    #pragma unroll
    for (int s = 0; s < 2; s++) {       // two K-halves of 64
        __syncthreads();
        #pragma unroll
        for (int i = 0; i < 4; i++) {   // 1024 16B-chunks per tile, 4/thread
            int q = t + 256 * i;
            int r = q >> 3, c = q & 7;
            uint4 va = t1[(size_t)(Abase + r) * 16 + s * 8 + c];
            *(uint4*)((char*)At + r * (LDSTRIDE * 2) + c * 16) = va;
            uint4 vb = t1[(size_t)(Bbase + r) * 16 + s * 8 + c];
            *(uint4*)((char*)Bt + r * (LDSTRIDE * 2) + c * 16) = vb;
        }
        __syncthreads();
        #pragma unroll
        for (int kk = 0; kk < 2; kk++) {
            int koffB = kk * 64 + quad * 16;  // byte offset in LDS row
            half8 af[4], bf[4];
            #pragma unroll
            for (int mi = 0; mi < 4; mi++) {
                int row = wm * 64 + mi * 16 + (lane & 15);
                af[mi] = *(const half8*)((const char*)At + row * (LDSTRIDE * 2) + koffB);
            }
            #pragma unroll
            for (int nj = 0; nj < 4; nj++) {
                int row = wn * 64 + nj * 16 + (lane & 15);
                bf[nj] = *(const half8*)((const char*)Bt + row * (LDSTRIDE * 2) + koffB);
            }
            #pragma unroll
            for (int mi = 0; mi < 4; mi++)
                #pragma unroll
                for (int nj = 0; nj < 4; nj++)
                    acc[mi][nj] = __builtin_amdgcn_mfma_f32_16x16x32_f16(
                        af[mi], bf[nj], acc[mi][nj], 0, 0, 0);
        }
    }

    // epilogue: l2 = sq[a]+sq[b]-2*dot ; emit strict a<b pairs below cutoff
    const float* sq1 = (const float*)(ws + OFF_SQ1);
    unsigned* cnt = (unsigned*)(ws + OFF_CNT);
    uint2* cand = (uint2*)(ws + OFF_CAND);
    f32x4 sqa[4];
    #pragma unroll
    for (int mi = 0; mi < 4; mi++)
        sqa[mi] = *(const f32x4*)&sq1[Abase + wm * 64 + mi * 16 + quad * 4];
    #pragma unroll
    for (int nj = 0; nj < 4; nj++) {
        int b = Bbase + wn * 64 + nj * 16 + (lane & 15);
        float sqb = sq1[b];
        #pragma unroll
        for (int mi = 0; mi < 4; mi++) {
            int abase = Abase + wm * 64 + mi * 16 + quad * 4;
            #pragma unroll
            for (int r = 0; r < 4; r++) {
                int a = abase + r;
                float l2 = sqa[mi][r] + sqb - 2.0f * acc[mi][nj][r];
                if (l2 < TAU && a < b) {
                    unsigned idx = atomicAdd(cnt, 1u);
                    if (idx < cap) cand[idx] = make_uint2((unsigned)a, (unsigned)b);
                }
            }
        }
    }
}

// ---- bwk1: column sums + total sq of f0 — ONLY if candidates exist --------
__global__ void bwk1(const float* __restrict__ src0, const float* __restrict__ tar0, char* __restrict__ ws) {
    if (*(volatile unsigned*)(ws + OFF_CNT) == 0) return;
    int d4 = blockIdx.x * 256 + threadIdx.x;   // float4-column, 0..511
    int rbase = blockIdx.y * 64;
    const float4* base = (const float4*)(rbase < B_ROWS ? src0 + (size_t)rbase * D0
                                                        : tar0 + (size_t)(rbase - B_ROWS) * D0);
    float4 cs = {0.f, 0.f, 0.f, 0.f};
    float sq = 0.f;
    for (int r = 0; r < 64; r++) {
        float4 v = base[(size_t)r * 512 + d4];
        cs.x += v.x; cs.y += v.y; cs.z += v.z; cs.w += v.w;
        sq += v.x * v.x + v.y * v.y + v.z * v.z + v.w * v.w;
    }
    float* m0 = (float*)(ws + OFF_M0);
    atomicAdd(&m0[d4 * 4 + 0], cs.x);
    atomicAdd(&m0[d4 * 4 + 1], cs.y);
    atomicAdd(&m0[d4 * 4 + 2], cs.z);
    atomicAdd(&m0[d4 * 4 + 3], cs.w);
    #pragma unroll
    for (int off = 32; off; off >>= 1) sq += __shfl_down(sq, off);
    __shared__ float red[4];
    int lane = threadIdx.x & 63, wave = threadIdx.x >> 6;
    if (lane == 0) red[wave] = sq;
    __syncthreads();
    if (threadIdx.x == 0)
        atomicAdd((double*)(ws + OFF_S0), (double)(red[0] + red[1] + red[2] + red[3]));
}

// ---- Phase B: exact f32 eval of candidates + bandwidth + final output -----
// bw computed redundantly per block (cold path only); last-done block writes
// d_out via device-scope done-counter (replaces bwk2 + finalk nodes).
__global__ void phaseB(const float* __restrict__ src0, const float* __restrict__ src1,
                       const float* __restrict__ tar0, const float* __restrict__ tar1,
                       char* __restrict__ ws, unsigned cap, float* __restrict__ out) {
    __shared__ double red[4];
    __shared__ float fred[4];
    __shared__ float bws;
    unsigned cnt = *(const unsigned*)(ws + OFF_CNT);   // block-uniform
    if (cnt > cap) cnt = cap;
    int lane = threadIdx.x & 63, wave = threadIdx.x >> 6;
    if (cnt > 0) {
        // ---- bandwidth0 = (2n*S0 - 2*||m||^2)/(n^2-n)/4 (per-block) ----
        const float* m0 = (const float*)(ws + OFF_M0);
        float s = 0.f;
        for (int j = threadIdx.x; j < 2048; j += 256) { float v = m0[j]; s += v * v; }
        #pragma unroll
        for (int off = 32; off; off >>= 1) s += __shfl_down(s, off);
        if (lane == 0) fred[wave] = s;
        __syncthreads();
        if (threadIdx.x == 0) {
            double m2 = (double)fred[0] + fred[1] + fred[2] + fred[3];
            double S0 = *(double*)(ws + OFF_S0);
            double lsum2 = 2.0 * (double)NTOT * S0 - 2.0 * m2;
            bws = (float)(lsum2 / ((double)NTOT * NTOT - NTOT) / 4.0);  // /mul^(5//2)
        }
        __syncthreads();
        float bw = bws;
        // ---- exact pair evaluation ----
        const uint2* cand = (const uint2*)(ws + OFF_CAND);
        unsigned gw = blockIdx.x * 4 + wave;
        unsigned nw = gridDim.x * 4;
        double lsum = 0.0;
        for (unsigned i = gw; i < cnt; i += nw) {
            uint2 p = cand[i];
            unsigned a = p.x, b = p.y;   // strict a<b by construction
            const float* ra0 = a < B_ROWS ? src0 + (size_t)a * D0 : tar0 + (size_t)(a - B_ROWS) * D0;
            const float* rb0 = b < B_ROWS ? src0 + (size_t)b * D0 : tar0 + (size_t)(b - B_ROWS) * D0;
            const float* ra1 = a < B_ROWS ? src1 + (size_t)a * D1 : tar1 + (size_t)(a - B_ROWS) * D1;
            const float* rb1 = b < B_ROWS ? src1 + (size_t)b * D1 : tar1 + (size_t)(b - B_ROWS) * D1;
            float d1;
            {
                float2 x = ((const float2*)ra1)[lane];
                float2 y = ((const float2*)rb1)[lane];
                float dx = x.x - y.x, dy = x.y - y.y;
                d1 = dx * dx + dy * dy;
            }
            float d0 = 0.f;
            #pragma unroll
            for (int j = 0; j < 8; j++) {
                float4 x = ((const float4*)ra0)[lane + 64 * j];
                float4 y = ((const float4*)rb0)[lane + 64 * j];
                float dx = x.x - y.x, dy = x.y - y.y, dz = x.z - y.z, dw = x.w - y.w;
                d0 += dx * dx + dy * dy + dz * dz + dw * dw;
            }
            #pragma unroll
            for (int off = 32; off; off >>= 1) {
                d0 += __shfl_down(d0, off);
                d1 += __shfl_down(d1, off);
            }
            if (lane == 0) {
                float k1 = expf(-d1 / 1.68f);
                float k0 = 0.f, bwj = bw;
                #pragma unroll
                for (int j = 0; j < 5; j++) { k0 += expf(-d0 / bwj); bwj *= 2.0f; }
                float sgn = ((a < B_ROWS) == (b < B_ROWS)) ? 1.0f : -1.0f;
                lsum += (double)(2.0f * sgn * k0 * k1);  // x2: (a,b) and (b,a)
            }
        }
        if (lane == 0) red[wave] = lsum;
        __syncthreads();
        if (threadIdx.x == 0)
            atomicAdd((double*)(ws + OFF_ACC), red[0] + red[1] + red[2] + red[3]);
    }
    // ---- completion: last block writes the mean (diag = 8192*5 exactly) ----
    __threadfence();
    if (threadIdx.x == 0) {
        unsigned d = atomicAdd((unsigned*)(ws + OFF_DONE), 1u);
        if (d == gridDim.x - 1) {
            double acc = atomicAdd((double*)(ws + OFF_ACC), 0.0);  // coherent read
            out[0] = (float)((acc + (double)NTOT * 5.0) / ((double)B_ROWS * (double)B_ROWS));
        }
    }
}

extern "C" void kernel_launch(void* const* d_in, const int* in_sizes, int n_in,
                              void* d_out, int out_size, void* d_ws, size_t ws_size,
                              hipStream_t stream) {
    const float* src0 = (const float*)d_in[0];
    const float* src1 = (const float*)d_in[1];
    const float* tar0 = (const float*)d_in[2];
    const float* tar1 = (const float*)d_in[3];
    char* ws = (char*)d_ws;
    unsigned cap = 0;
    if (ws_size > (size_t)OFF_CAND + 8) {
        size_t c = (ws_size - OFF_CAND) / 8;
        if (c > (size_t)4 * 1024 * 1024) c = (size_t)4 * 1024 * 1024;
        cap = (unsigned)c;
    }
    p0a<<<2048, 256, 0, stream>>>(src1, tar1, ws);
    phaseA<<<2080, 256, 0, stream>>>(ws, cap);
    bwk1<<<dim3(2, 128), 256, 0, stream>>>(src0, tar0, ws);
    phaseB<<<64, 256, 0, stream>>>(src0, src1, tar0, tar1, ws, cap, (float*)d_out);
}